// Round 2
// baseline (296.748 us; speedup 1.0000x reference)
//
#include <hip/hip_runtime.h>
#include <cstdint>
#include <cstddef>

#define T_DIM 256
#define H_DIM 4096
#define I_DIM 14336
// GROUP_SIZE=64 == BK: one (scale,zero) per row per K-tile.

typedef __attribute__((ext_vector_type(8))) short s8v;   // 8 bf16
typedef __attribute__((ext_vector_type(4))) float f4v;   // MFMA C/D frag

static constexpr size_t XS_BYTES   = (size_t)T_DIM * H_DIM * 2;   // 2 MiB
static constexpr size_t ACT_OFF    = XS_BYTES;
static constexpr size_t ACT_BYTES  = (size_t)T_DIM * I_DIM * 2;   // 7 MiB
static constexpr size_t PART_OFF   = ACT_OFF + ACT_BYTES;
static constexpr size_t PART_BYTES = 8ull * T_DIM * H_DIM * 4;    // 32 MiB
static constexpr size_t WS_NEEDED  = PART_OFF + PART_BYTES;

__device__ __forceinline__ unsigned short f2bf(float f) {
    unsigned u = __builtin_bit_cast(unsigned, f);
    u += 0x7fffu + ((u >> 16) & 1u);
    return (unsigned short)(u >> 16);
}

__device__ __forceinline__ s8v dq8(const int4 qa, const int4 qb, float s, float ns) {
    union { unsigned short u[8]; s8v v; } r;
    r.u[0] = f2bf(fmaf((float)qa.x, s, ns));
    r.u[1] = f2bf(fmaf((float)qa.y, s, ns));
    r.u[2] = f2bf(fmaf((float)qa.z, s, ns));
    r.u[3] = f2bf(fmaf((float)qa.w, s, ns));
    r.u[4] = f2bf(fmaf((float)qb.x, s, ns));
    r.u[5] = f2bf(fmaf((float)qb.y, s, ns));
    r.u[6] = f2bf(fmaf((float)qb.z, s, ns));
    r.u[7] = f2bf(fmaf((float)qb.w, s, ns));
    return r.v;
}

// ---------------------------------------------------------------------------
// k_prep: x fp32 [256,4096] -> bf16, K-tile-major LINEAR: shorts at
// kt*16384 + row*64 + col. (Swizzle now happens at the GEMM ds_write side.)
// ---------------------------------------------------------------------------
__global__ __launch_bounds__(256) void k_prep(const float* __restrict__ x,
                                              unsigned short* __restrict__ xs) {
    int gs   = blockIdx.x * 256 + threadIdx.x;
    int kt   = gs >> 11;
    int rem  = gs & 2047;
    int row  = rem >> 3;
    int slot = rem & 7;
    const float* xp = x + (size_t)row * H_DIM + kt * 64 + slot * 8;
    float4 a = *(const float4*)xp;
    float4 b = *(const float4*)(xp + 4);
    union { unsigned short u[8]; s8v v; } r;
    r.u[0] = f2bf(a.x); r.u[1] = f2bf(a.y); r.u[2] = f2bf(a.z); r.u[3] = f2bf(a.w);
    r.u[4] = f2bf(b.x); r.u[5] = f2bf(b.y); r.u[6] = f2bf(b.z); r.u[7] = f2bf(b.w);
    *(s8v*)(xs + (size_t)kt * 16384 + (size_t)row * 64 + (size_t)slot * 8) = r.v;
}

// ---------------------------------------------------------------------------
// k_gemm1: fused gate/up GEMM, M=256 x BN=64, K=4096, grid 224.
// Reg-staged depth-1 prefetch + double-buffered LDS (2x48 KiB).
// Per tile: load(t+2)->regs ; compute(t) ; sync ; dequant+store(t+1) ; sync.
// ---------------------------------------------------------------------------
struct P1 { int4 x0, x1, x2, x3, q1a, q1b, q3a, q3b; float s1, z1, s3, z3; };

__global__ __launch_bounds__(512, 2) void k_gemm1(
    const int* __restrict__ w1q, const float* __restrict__ w1s, const float* __restrict__ w1z,
    const int* __restrict__ w3q, const float* __restrict__ w3s, const float* __restrict__ w3z,
    const unsigned short* __restrict__ xs, unsigned short* __restrict__ act)
{
    __shared__ unsigned char lds[2][49152];   // per buf: x 32K @0, w1 8K @32768, w3 8K @40960
    const int tid  = threadIdx.x;
    const int blk  = blockIdx.x;
    const int n0   = blk * 64;
    const int wid  = tid >> 6;
    const int lane = tid & 63;
    const int wr   = wid >> 1;             // 0..3 -> M base wr*64
    const int wc   = wid & 1;              // 0..1 -> N base wc*32
    const int lr   = lane & 15;
    const int lkb  = lane >> 4;
    const int aswz = (lr & 7) << 4;

    // staging map: sr = row (0..63) [x rows sr+64j], sl = 16B slot (0..7)
    const int sr = tid >> 3, sl = tid & 7;
    const int sbyte = sr * 128 + ((sl * 16) ^ ((sr & 7) << 4));  // swizzled LDS byte
    const int4*  xbase = (const int4*)xs;                        // idx kt*2048+row*8+slot
    const size_t wrow  = (size_t)(n0 + sr) * H_DIM;
    const float* s1p = w1s + (size_t)(n0 + sr) * 64;
    const float* z1p = w1z + (size_t)(n0 + sr) * 64;
    const float* s3p = w3s + (size_t)(n0 + sr) * 64;
    const float* z3p = w3z + (size_t)(n0 + sr) * 64;

    f4v accg[4][2], accu[4][2];
    const f4v fz = {0.f, 0.f, 0.f, 0.f};
    #pragma unroll
    for (int i = 0; i < 4; ++i)
        #pragma unroll
        for (int j = 0; j < 2; ++j) { accg[i][j] = fz; accu[i][j] = fz; }

    auto load = [&](int kt, P1& p) {
        const int4* xp = xbase + kt * 2048 + sr * 8 + sl;
        p.x0 = xp[0]; p.x1 = xp[512]; p.x2 = xp[1024]; p.x3 = xp[1536];
        const int4* p1 = (const int4*)(w1q + wrow + kt * 64 + sl * 8);
        const int4* p3 = (const int4*)(w3q + wrow + kt * 64 + sl * 8);
        p.q1a = p1[0]; p.q1b = p1[1]; p.q3a = p3[0]; p.q3b = p3[1];
        p.s1 = s1p[kt]; p.z1 = z1p[kt]; p.s3 = s3p[kt]; p.z3 = z3p[kt];
    };
    auto store = [&](const P1& p, unsigned char* b) {
        *(int4*)(b + sbyte)         = p.x0;
        *(int4*)(b + sbyte + 8192)  = p.x1;
        *(int4*)(b + sbyte + 16384) = p.x2;
        *(int4*)(b + sbyte + 24576) = p.x3;
        *(s8v*)(b + 32768 + sbyte) = dq8(p.q1a, p.q1b, p.s1, -p.z1 * p.s1);
        *(s8v*)(b + 40960 + sbyte) = dq8(p.q3a, p.q3b, p.s3, -p.z3 * p.s3);
    };
    auto compute = [&](const unsigned char* b) {
        #pragma unroll
        for (int kf = 0; kf < 2; ++kf) {
            const int kb = (kf * 64 + lkb * 16) ^ aswz;
            s8v a[4];
            #pragma unroll
            for (int mf = 0; mf < 4; ++mf)
                a[mf] = *(const s8v*)(b + (wr * 64 + mf * 16 + lr) * 128 + kb);
            s8v b1[2], b3[2];
            #pragma unroll
            for (int nf = 0; nf < 2; ++nf) {
                const int rbo = (wc * 32 + nf * 16 + lr) * 128 + kb;
                b1[nf] = *(const s8v*)(b + 32768 + rbo);
                b3[nf] = *(const s8v*)(b + 40960 + rbo);
            }
            #pragma unroll
            for (int mf = 0; mf < 4; ++mf)
                #pragma unroll
                for (int nf = 0; nf < 2; ++nf) {
                    accg[mf][nf] = __builtin_amdgcn_mfma_f32_16x16x32_bf16(a[mf], b1[nf], accg[mf][nf], 0, 0, 0);
                    accu[mf][nf] = __builtin_amdgcn_mfma_f32_16x16x32_bf16(a[mf], b3[nf], accu[mf][nf], 0, 0, 0);
                }
        }
    };

    P1 A, B;
    load(0, A);
    store(A, lds[0]);
    load(1, B);
    __syncthreads();

    for (int it = 0; it < 32; ++it) {
        const int t = it * 2;
        load(t + 2 > 63 ? 63 : t + 2, A);   // prefetch, overlaps compute below
        compute(lds[0]);                    // tile t
        __syncthreads();
        store(B, lds[1]);                   // tile t+1
        __syncthreads();
        load(t + 3 > 63 ? 63 : t + 3, B);
        compute(lds[1]);                    // tile t+1
        __syncthreads();
        store(A, lds[0]);                   // tile t+2 (last iter: dead, harmless)
        __syncthreads();
    }

    // epilogue: act (linear K-tile-major layout, tile = this block)
    unsigned char* actb = (unsigned char*)act + (size_t)blk * 32768;
    #pragma unroll
    for (int mf = 0; mf < 4; ++mf)
        #pragma unroll
        for (int nf = 0; nf < 2; ++nf)
            #pragma unroll
            for (int r = 0; r < 4; ++r) {
                const int m  = wr * 64 + mf * 16 + lkb * 4 + r;
                const int nl = wc * 32 + nf * 16 + lr;
                float g = accg[mf][nf][r];
                float u = accu[mf][nf][r];
                float sg = g / (1.0f + __expf(-g));
                *(unsigned short*)(actb + m * 128 + nl * 2) = f2bf(sg * u);
            }
}

// ---------------------------------------------------------------------------
// k_gemm2: act[256,I] @ w2[H,I]^T, M=256 x BN=128, 8 K-chunks x 28 tiles.
// Same reg-staged prefetch structure. fp32 partials -> k_reduce.
// ---------------------------------------------------------------------------
struct P2 { int4 a0, a1, a2, a3, q0, q1, q2, q3; float s2, z2; };

template<bool ATOMIC>
__global__ __launch_bounds__(512, 2) void k_gemm2(
    const int* __restrict__ w2q, const float* __restrict__ w2s, const float* __restrict__ w2z,
    const unsigned short* __restrict__ act, float* __restrict__ outp)
{
    __shared__ unsigned char lds[2][49152];   // per buf: act 32K @0, w2 16K @32768
    const int tid  = threadIdx.x;
    const int nb   = blockIdx.x & 31;
    const int kc   = blockIdx.x >> 5;
    const int n0   = nb * 128;
    const int wid  = tid >> 6;
    const int lane = tid & 63;
    const int wr   = wid >> 2;             // 0..1 -> M base wr*128
    const int wc   = wid & 3;              // 0..3 -> N base wc*32
    const int lr   = lane & 15;
    const int lkb  = lane >> 4;
    const int aswz = (lr & 7) << 4;

    // act staging: rows sr+64j, slot sl
    const int sr = tid >> 3, sl = tid & 7;
    const int abyte = sr * 128 + ((sl * 16) ^ ((sr & 7) << 4));
    // w2 staging: row r2 (0..127), 4 threads/row, 16 ints each -> 2 LDS slots
    const int r2 = tid >> 2, sq = tid & 3;
    const int wb0 = r2 * 128 + (((sq * 2) * 16)     ^ ((r2 & 7) << 4));
    const int wb1 = r2 * 128 + (((sq * 2 + 1) * 16) ^ ((r2 & 7) << 4));
    const int4*  abase = (const int4*)act;
    const size_t w2row = (size_t)(n0 + r2) * I_DIM;
    const float* s2p = w2s + (size_t)(n0 + r2) * 224;
    const float* z2p = w2z + (size_t)(n0 + r2) * 224;

    f4v acc[8][2];
    const f4v fz = {0.f, 0.f, 0.f, 0.f};
    #pragma unroll
    for (int i = 0; i < 8; ++i) { acc[i][0] = fz; acc[i][1] = fz; }

    auto load = [&](int kt, P2& p) {
        const int4* ap = abase + kt * 2048 + sr * 8 + sl;
        p.a0 = ap[0]; p.a1 = ap[512]; p.a2 = ap[1024]; p.a3 = ap[1536];
        const int4* wp = (const int4*)(w2q + w2row + kt * 64 + sq * 16);
        p.q0 = wp[0]; p.q1 = wp[1]; p.q2 = wp[2]; p.q3 = wp[3];
        p.s2 = s2p[kt]; p.z2 = z2p[kt];
    };
    auto store = [&](const P2& p, unsigned char* b) {
        *(int4*)(b + abyte)         = p.a0;
        *(int4*)(b + abyte + 8192)  = p.a1;
        *(int4*)(b + abyte + 16384) = p.a2;
        *(int4*)(b + abyte + 24576) = p.a3;
        float ns = -p.z2 * p.s2;
        *(s8v*)(b + 32768 + wb0) = dq8(p.q0, p.q1, p.s2, ns);
        *(s8v*)(b + 32768 + wb1) = dq8(p.q2, p.q3, p.s2, ns);
    };
    auto compute = [&](const unsigned char* b) {
        #pragma unroll
        for (int kf = 0; kf < 2; ++kf) {
            const int kb = (kf * 64 + lkb * 16) ^ aswz;
            s8v bfr[2];
            #pragma unroll
            for (int nf = 0; nf < 2; ++nf)
                bfr[nf] = *(const s8v*)(b + 32768 + (wc * 32 + nf * 16 + lr) * 128 + kb);
            #pragma unroll
            for (int mf = 0; mf < 8; ++mf) {
                s8v a = *(const s8v*)(b + (wr * 128 + mf * 16 + lr) * 128 + kb);
                acc[mf][0] = __builtin_amdgcn_mfma_f32_16x16x32_bf16(a, bfr[0], acc[mf][0], 0, 0, 0);
                acc[mf][1] = __builtin_amdgcn_mfma_f32_16x16x32_bf16(a, bfr[1], acc[mf][1], 0, 0, 0);
            }
        }
    };

    const int kt0 = kc * 28;
    P2 A, B;
    load(kt0, A);
    store(A, lds[0]);
    load(kt0 + 1, B);
    __syncthreads();

    for (int it = 0; it < 14; ++it) {
        const int t = it * 2;
        load(kt0 + (t + 2 > 27 ? 27 : t + 2), A);
        compute(lds[0]);
        __syncthreads();
        store(B, lds[1]);
        __syncthreads();
        load(kt0 + (t + 3 > 27 ? 27 : t + 3), B);
        compute(lds[1]);
        __syncthreads();
        store(A, lds[0]);
        __syncthreads();
    }

    float* pout = outp + (ATOMIC ? 0 : (size_t)kc * ((size_t)T_DIM * H_DIM));
    #pragma unroll
    for (int mf = 0; mf < 8; ++mf)
        #pragma unroll
        for (int nf = 0; nf < 2; ++nf)
            #pragma unroll
            for (int r = 0; r < 4; ++r) {
                const int m = wr * 128 + mf * 16 + lkb * 4 + r;
                const int n = n0 + wc * 32 + nf * 16 + lr;
                if (ATOMIC) atomicAdd(&outp[(size_t)m * H_DIM + n], acc[mf][nf][r]);
                else        pout[(size_t)m * H_DIM + n] = acc[mf][nf][r];
            }
}

__global__ __launch_bounds__(256) void k_reduce(const f4v* __restrict__ p,
                                                f4v* __restrict__ o) {
    int i = blockIdx.x * 256 + threadIdx.x;
    f4v s = p[i];
    #pragma unroll
    for (int c = 1; c < 8; ++c) s += p[(size_t)c * 262144 + i];
    o[i] = s;
}

__global__ __launch_bounds__(256) void k_zero(f4v* __restrict__ o) {
    o[blockIdx.x * 256 + threadIdx.x] = (f4v){0.f, 0.f, 0.f, 0.f};
}

extern "C" void kernel_launch(void* const* d_in, const int* in_sizes, int n_in,
                              void* d_out, int out_size, void* d_ws, size_t ws_size,
                              hipStream_t stream) {
    const float* x   = (const float*)d_in[0];
    const int*   w1q = (const int*)  d_in[1];
    const float* w1s = (const float*)d_in[2];
    const float* w1z = (const float*)d_in[3];
    const int*   w3q = (const int*)  d_in[4];
    const float* w3s = (const float*)d_in[5];
    const float* w3z = (const float*)d_in[6];
    const int*   w2q = (const int*)  d_in[7];
    const float* w2s = (const float*)d_in[8];
    const float* w2z = (const float*)d_in[9];
    float* outp = (float*)d_out;

    unsigned short* xs  = (unsigned short*)d_ws;
    unsigned short* act = (unsigned short*)((char*)d_ws + ACT_OFF);
    float*          prt = (float*)((char*)d_ws + PART_OFF);
    const bool partials = (ws_size >= WS_NEEDED);

    k_prep<<<512, 256, 0, stream>>>(x, xs);
    k_gemm1<<<224, 512, 0, stream>>>(w1q, w1s, w1z, w3q, w3s, w3z, xs, act);
    if (partials) {
        k_gemm2<false><<<256, 512, 0, stream>>>(w2q, w2s, w2z, act, prt);
        k_reduce<<<1024, 256, 0, stream>>>((const f4v*)prt, (f4v*)outp);
    } else {
        k_zero<<<1024, 256, 0, stream>>>((f4v*)outp);
        k_gemm2<true><<<256, 512, 0, stream>>>(w2q, w2s, w2z, act, outp);
    }
}